// Round 3
// baseline (282.290 us; speedup 1.0000x reference)
//
#include <hip/hip_runtime.h>

#define BATCH 8
#define SEQL 16384
#define NCH 128
#define NH 4
#define HD 32
#define GEPS 1e-5f

typedef __bf16 bf16x8 __attribute__((ext_vector_type(8)));
typedef __bf16 bf16x4 __attribute__((ext_vector_type(4)));
typedef float f32x4 __attribute__((ext_vector_type(4)));

// ---- workspace byte offsets ----
#define WKV_B   0          // 256*128 bf16 = 64 KiB   [o'][c], o' = o-128 (k:0..127, v:128..255)
#define WQ_B    65536      // 128*128 bf16 = 32 KiB   [o][c]
#define WO_B    98304      // 128*128 bf16 = 32 KiB   [o][c]
#define CTXB_B  131072     // 8*4*32*32 bf16 = 64 KiB [b][h][c][d]
#define CTXF_B  196608     // 8*4*32*32 f32 = 128 KiB
#define ZF_B    327680     // 8*128 f32 = 4 KiB
#define GNS_B   331776     // 8*2 f32
#define GNF_B   331840     // 8*2 f32
#define ZERO_BYTES (131072 + 4096 + 64 + 64)

__global__ void k_prep(const float* __restrict__ wqkv, const float* __restrict__ wout,
                       char* __restrict__ wsb) {
    int i = blockIdx.x * 256 + threadIdx.x;
    __bf16* wkvb = (__bf16*)(wsb + WKV_B);
    __bf16* wqb  = (__bf16*)(wsb + WQ_B);
    __bf16* wob  = (__bf16*)(wsb + WO_B);
    if (i < 384 * 128) {
        int o = i >> 7, c = i & 127;
        __bf16 v = (__bf16)wqkv[i];
        if (o < 128) wqb[o * 128 + c] = v;
        else         wkvb[(o - 128) * 128 + c] = v;
    }
    if (i < 128 * 128) wob[i] = (__bf16)wout[i];
}

// Pass 1: kv = Wkv @ x (MFMA); ek = exp(k); ctx_raw += ek (outer) v (MFMA); Z += ek
__global__ __launch_bounds__(256, 3) void k_pass1(const float* __restrict__ x,
                                                  char* __restrict__ wsb) {
    __shared__ __attribute__((aligned(16))) __bf16 xb[8352];
    __shared__ __attribute__((aligned(16))) __bf16 ekv[16464];
    const int t = threadIdx.x;
    const int lane = t & 63, wave = t >> 6;
    const int n16 = lane & 15, q = lane >> 4;
    const int batch = blockIdx.x >> 7, sub = blockIdx.x & 127;   // 128 blocks/batch
    const __bf16* __restrict__ wkvb = (const __bf16*)(wsb + WKV_B);

    f32x4 ctxacc[2][2];
#pragma unroll
    for (int i = 0; i < 2; i++)
#pragma unroll
        for (int j = 0; j < 2; j++) ctxacc[i][j] = (f32x4){0.f, 0.f, 0.f, 0.f};
    float zacc[4][4];
#pragma unroll
    for (int i = 0; i < 4; i++)
#pragma unroll
        for (int j = 0; j < 4; j++) zacc[i][j] = 0.f;

    for (int rep = 0; rep < 2; rep++) {
        const int chunk = sub + rep * 128;
        const float* xg = x + (size_t)(batch * SEQL + chunk * 64) * NCH;
        __syncthreads();
        // stage x -> bf16 LDS in B-operand layout
#pragma unroll
        for (int r = 0; r < 8; r++) {
            int e = t + r * 256;
            int tok = e >> 5, c4 = (e & 31) * 4;
            float4 v = ((const float4*)xg)[e];
            bf16x4 h; h.x = (__bf16)v.x; h.y = (__bf16)v.y; h.z = (__bf16)v.z; h.w = (__bf16)v.w;
            *(bf16x4*)&xb[(c4 >> 5) * 2088 + ((c4 >> 3) & 3) * 520 + tok * 8 + (c4 & 7)] = h;
        }
        __syncthreads();
        // KV GEMM: D[o][t], o = wave*64 + mt*16 + (row), t = nt*16 + (col)
        f32x4 kvacc[4][4];
#pragma unroll
        for (int i = 0; i < 4; i++)
#pragma unroll
            for (int j = 0; j < 4; j++) kvacc[i][j] = (f32x4){0.f, 0.f, 0.f, 0.f};
#pragma unroll
        for (int ks = 0; ks < 4; ks++) {
            bf16x8 awk[4];
#pragma unroll
            for (int mt = 0; mt < 4; mt++)
                awk[mt] = *(const bf16x8*)&wkvb[(wave * 64 + mt * 16 + n16) * 128 + ks * 32 + q * 8];
            bf16x8 b[4];
#pragma unroll
            for (int nt = 0; nt < 4; nt++)
                b[nt] = *(const bf16x8*)&xb[ks * 2088 + q * 520 + (nt * 16 + n16) * 8];
#pragma unroll
            for (int mt = 0; mt < 4; mt++)
#pragma unroll
                for (int nt = 0; nt < 4; nt++)
                    kvacc[mt][nt] = __builtin_amdgcn_mfma_f32_16x16x32_bf16(
                        awk[mt], b[nt], kvacc[mt][nt], 0, 0, 0);
        }
        // exp (k-waves), accumulate Z, write ekv LDS in frag-friendly layout
#pragma unroll
        for (int mt = 0; mt < 4; mt++)
#pragma unroll
            for (int nt = 0; nt < 4; nt++) {
                int tt = nt * 16 + n16;
                int base = (tt >> 5) * 8232 + ((tt >> 3) & 3) * 2056 + (tt & 7);
#pragma unroll
                for (int r = 0; r < 4; r++) {
                    float vv = kvacc[mt][nt][r];
                    if (wave < 2) { vv = __expf(vv); zacc[mt][r] += vv; }
                    int o = wave * 64 + mt * 16 + q * 4 + r;
                    ekv[base + o * 8] = (__bf16)vv;
                }
            }
        __syncthreads();
        // ctx MFMA: wave = head h; A = ek[c][t] (c = h*32..), B = v[d][t]
#pragma unroll
        for (int ks2 = 0; ks2 < 2; ks2++) {
            bf16x8 ea[2], vb[2];
#pragma unroll
            for (int ml = 0; ml < 2; ml++) {
                ea[ml] = *(const bf16x8*)&ekv[ks2 * 8232 + q * 2056 + (wave * 32 + ml * 16 + n16) * 8];
                vb[ml] = *(const bf16x8*)&ekv[ks2 * 8232 + q * 2056 + (128 + wave * 32 + ml * 16 + n16) * 8];
            }
#pragma unroll
            for (int ml = 0; ml < 2; ml++)
#pragma unroll
                for (int nl = 0; nl < 2; nl++)
                    ctxacc[ml][nl] = __builtin_amdgcn_mfma_f32_16x16x32_bf16(
                        ea[ml], vb[nl], ctxacc[ml][nl], 0, 0, 0);
        }
    }
    // ctx atomics: lane holds ctx[c = ml*16+q*4+r][d = nl*16+n16] for head=wave
    float* ctxf = (float*)(wsb + CTXF_B) + ((size_t)(batch * 4 + wave) * 32) * 32;
#pragma unroll
    for (int ml = 0; ml < 2; ml++)
#pragma unroll
        for (int nl = 0; nl < 2; nl++)
#pragma unroll
            for (int r = 0; r < 4; r++)
                atomicAdd(&ctxf[(ml * 16 + q * 4 + r) * 32 + nl * 16 + n16], ctxacc[ml][nl][r]);
    // Z: sum over tokens = butterfly over n16 lanes
    if (wave < 2) {
        float* Zf = (float*)(wsb + ZF_B) + batch * 128;
#pragma unroll
        for (int mt = 0; mt < 4; mt++)
#pragma unroll
            for (int r = 0; r < 4; r++) {
                float z = zacc[mt][r];
                z += __shfl_xor(z, 1); z += __shfl_xor(z, 2);
                z += __shfl_xor(z, 4); z += __shfl_xor(z, 8);
                if (n16 == 0) atomicAdd(&Zf[wave * 64 + mt * 16 + q * 4 + r], z);
            }
    }
}

__global__ void k_ctxnorm(char* __restrict__ wsb) {
    int i = blockIdx.x * 256 + threadIdx.x;
    if (i < BATCH * NH * HD * HD) {
        const float* ctxf = (const float*)(wsb + CTXF_B);
        const float* Zf = (const float*)(wsb + ZF_B);
        __bf16* ctxb = (__bf16*)(wsb + CTXB_B);
        int c = (i >> 5) & 31, h = (i >> 10) & 3, b = i >> 12;
        ctxb[i] = (__bf16)(ctxf[i] / Zf[b * 128 + h * 32 + c]);
    }
}

// Pass 2: q = Wq @ x (MFMA); softmax over head-dim in registers; attn = ctx @ p (MFMA);
// out = Wout @ attn + bias (MFMA); GN partial sums; store pre-GN out.
// LDS: bufA holds x then attn; bufB holds p. 33.4 KB -> 4 blocks/CU.
__global__ __launch_bounds__(256, 4) void k_pass2(const float* __restrict__ x,
                                                  const float* __restrict__ bout,
                                                  char* __restrict__ wsb,
                                                  float* __restrict__ out) {
    __shared__ __attribute__((aligned(16))) __bf16 bufA[8352];
    __shared__ __attribute__((aligned(16))) __bf16 bufB[8352];
    __shared__ float gred[8];
    const int t = threadIdx.x;
    const int lane = t & 63, wave = t >> 6;       // wave == head h
    const int n16 = lane & 15, q = lane >> 4;
    const int batch = blockIdx.x >> 8, chunk = blockIdx.x & 255;
    const __bf16* __restrict__ wqb = (const __bf16*)(wsb + WQ_B);
    const __bf16* __restrict__ wob = (const __bf16*)(wsb + WO_B);
    const __bf16* __restrict__ ctxb = (const __bf16*)(wsb + CTXB_B);

    const size_t tok0 = (size_t)batch * SEQL + chunk * 64;
    const float* xg = x + tok0 * NCH;
    // stage x -> bufA (B-operand layout)
#pragma unroll
    for (int r = 0; r < 8; r++) {
        int e = t + r * 256;
        int tok = e >> 5, c4 = (e & 31) * 4;
        float4 v = ((const float4*)xg)[e];
        bf16x4 h; h.x = (__bf16)v.x; h.y = (__bf16)v.y; h.z = (__bf16)v.z; h.w = (__bf16)v.w;
        *(bf16x4*)&bufA[(c4 >> 5) * 2088 + ((c4 >> 3) & 3) * 520 + tok * 8 + (c4 & 7)] = h;
    }
    // A-fragments (short lifetimes: compiler sinks to first use)
    bf16x8 aq[2][4];
#pragma unroll
    for (int ml = 0; ml < 2; ml++)
#pragma unroll
        for (int ks = 0; ks < 4; ks++)
            aq[ml][ks] = *(const bf16x8*)&wqb[(wave * 32 + ml * 16 + n16) * 128 + ks * 32 + q * 8];
    bf16x8 actx[2];
#pragma unroll
    for (int ml = 0; ml < 2; ml++)
        actx[ml] = *(const bf16x8*)&ctxb[((size_t)(batch * 4 + wave) * 32 + ml * 16 + n16) * 32 + q * 8];
    __syncthreads();

    // Wq GEMM: wave handles its head's 32 q-channels
    f32x4 qacc[2][4];
#pragma unroll
    for (int i = 0; i < 2; i++)
#pragma unroll
        for (int j = 0; j < 4; j++) qacc[i][j] = (f32x4){0.f, 0.f, 0.f, 0.f};
#pragma unroll
    for (int ks = 0; ks < 4; ks++) {
        bf16x8 b[4];
#pragma unroll
        for (int nt = 0; nt < 4; nt++)
            b[nt] = *(const bf16x8*)&bufA[ks * 2088 + q * 520 + (nt * 16 + n16) * 8];
#pragma unroll
        for (int ml = 0; ml < 2; ml++)
#pragma unroll
            for (int nt = 0; nt < 4; nt++)
                qacc[ml][nt] = __builtin_amdgcn_mfma_f32_16x16x32_bf16(
                    aq[ml][ks], b[nt], qacc[ml][nt], 0, 0, 0);
    }
    // softmax over the 32 head channels, in registers + 2 shuffles
#pragma unroll
    for (int nt = 0; nt < 4; nt++) {
        float ss = 0.f;
#pragma unroll
        for (int ml = 0; ml < 2; ml++)
#pragma unroll
            for (int r = 0; r < 4; r++) {
                float e = __expf(qacc[ml][nt][r]);
                qacc[ml][nt][r] = e;
                ss += e;
            }
        ss += __shfl_xor(ss, 16);
        ss += __shfl_xor(ss, 32);
        float inv = 0.17677669529663687f / ss;   // (1/sqrt(32)) / denom
#pragma unroll
        for (int ml = 0; ml < 2; ml++)
#pragma unroll
            for (int r = 0; r < 4; r++) qacc[ml][nt][r] *= inv;
    }
    __syncthreads();   // all waves done reading bufA (x); bufA is reusable
    // write p -> bufB (wave-private head region)
#pragma unroll
    for (int ml = 0; ml < 2; ml++)
#pragma unroll
        for (int nt = 0; nt < 4; nt++) {
            bf16x4 h;
            h.x = (__bf16)qacc[ml][nt][0]; h.y = (__bf16)qacc[ml][nt][1];
            h.z = (__bf16)qacc[ml][nt][2]; h.w = (__bf16)qacc[ml][nt][3];
            *(bf16x4*)&bufB[wave * 2088 + (ml * 2 + (q >> 1)) * 520 +
                            (nt * 16 + n16) * 8 + (q & 1) * 4] = h;
        }
    // wave-private round-trip: LDS drain, no block barrier needed
    __builtin_amdgcn_fence(__ATOMIC_ACQ_REL, "workgroup");
    // attn MFMA: A = ctx[h] (32c x 32d), B = p[h] (32d x 64t); write into bufA
#pragma unroll
    for (int ml = 0; ml < 2; ml++)
#pragma unroll
        for (int nt = 0; nt < 4; nt++) {
            bf16x8 pb = *(const bf16x8*)&bufB[wave * 2088 + q * 520 + (nt * 16 + n16) * 8];
            f32x4 aacc = __builtin_amdgcn_mfma_f32_16x16x32_bf16(
                actx[ml], pb, (f32x4){0.f, 0.f, 0.f, 0.f}, 0, 0, 0);
            bf16x4 h;
            h.x = (__bf16)aacc[0]; h.y = (__bf16)aacc[1];
            h.z = (__bf16)aacc[2]; h.w = (__bf16)aacc[3];
            *(bf16x4*)&bufA[wave * 2088 + (ml * 2 + (q >> 1)) * 520 +
                            (nt * 16 + n16) * 8 + (q & 1) * 4] = h;
        }
    __syncthreads();
    // Wout GEMM: wave covers out channels o = wave*32 + ml*16 + ...
    f32x4 oacc[2][4];
#pragma unroll
    for (int i = 0; i < 2; i++)
#pragma unroll
        for (int j = 0; j < 4; j++) oacc[i][j] = (f32x4){0.f, 0.f, 0.f, 0.f};
#pragma unroll
    for (int ks = 0; ks < 4; ks++) {
        bf16x8 ao = *(const bf16x8*)&wob[(wave * 32 + 0 * 16 + n16) * 128 + ks * 32 + q * 8];
        bf16x8 ao1 = *(const bf16x8*)&wob[(wave * 32 + 1 * 16 + n16) * 128 + ks * 32 + q * 8];
        bf16x8 b[4];
#pragma unroll
        for (int nt = 0; nt < 4; nt++)
            b[nt] = *(const bf16x8*)&bufA[ks * 2088 + q * 520 + (nt * 16 + n16) * 8];
#pragma unroll
        for (int nt = 0; nt < 4; nt++) {
            oacc[0][nt] = __builtin_amdgcn_mfma_f32_16x16x32_bf16(ao, b[nt], oacc[0][nt], 0, 0, 0);
            oacc[1][nt] = __builtin_amdgcn_mfma_f32_16x16x32_bf16(ao1, b[nt], oacc[1][nt], 0, 0, 0);
        }
    }
    // epilogue: bias, GN sums, store
    float4 bias[2];
#pragma unroll
    for (int ml = 0; ml < 2; ml++)
        bias[ml] = *(const float4*)&bout[wave * 32 + ml * 16 + q * 4];
    float s1 = 0.f, s2 = 0.f;
#pragma unroll
    for (int ml = 0; ml < 2; ml++)
#pragma unroll
        for (int nt = 0; nt < 4; nt++) {
            float4 vv;
            vv.x = oacc[ml][nt][0] + bias[ml].x;
            vv.y = oacc[ml][nt][1] + bias[ml].y;
            vv.z = oacc[ml][nt][2] + bias[ml].z;
            vv.w = oacc[ml][nt][3] + bias[ml].w;
            s1 += vv.x + vv.y + vv.z + vv.w;
            s2 += vv.x * vv.x + vv.y * vv.y + vv.z * vv.z + vv.w * vv.w;
            *(float4*)&out[(tok0 + nt * 16 + n16) * NCH + wave * 32 + ml * 16 + q * 4] = vv;
        }
#pragma unroll
    for (int off = 32; off > 0; off >>= 1) {
        s1 += __shfl_xor(s1, off);
        s2 += __shfl_xor(s2, off);
    }
    if (lane == 0) { gred[wave] = s1; gred[4 + wave] = s2; }
    __syncthreads();
    if (t == 0) {
        float* gns = (float*)(wsb + GNS_B);
        atomicAdd(&gns[batch * 2 + 0], gred[0] + gred[1] + gred[2] + gred[3]);
        atomicAdd(&gns[batch * 2 + 1], gred[4] + gred[5] + gred[6] + gred[7]);
    }
}

__global__ void k_gnfinal(char* __restrict__ wsb) {
    int b = threadIdx.x;
    if (b < BATCH) {
        const float n = (float)NCH * (float)SEQL;
        const float* gns = (const float*)(wsb + GNS_B);
        float* gnf = (float*)(wsb + GNF_B);
        float mean = gns[b * 2] / n;
        float var = gns[b * 2 + 1] / n - mean * mean;
        gnf[b * 2] = mean;
        gnf[b * 2 + 1] = rsqrtf(var + GEPS);
    }
}

__global__ __launch_bounds__(256) void k_gnorm(float* __restrict__ out,
                                               const char* __restrict__ wsb,
                                               const float* __restrict__ gw,
                                               const float* __restrict__ gb) {
    size_t i4 = (size_t)blockIdx.x * 256 + threadIdx.x;
    int b = (int)(i4 >> 19);
    int c4 = (int)(i4 & 31);
    const float* gnf = (const float*)(wsb + GNF_B);
    float mean = gnf[b * 2], rstd = gnf[b * 2 + 1];
    float4 w = *(const float4*)&gw[c4 * 4];
    float4 bb = *(const float4*)&gb[c4 * 4];
    float4 v = ((float4*)out)[i4];
    v.x = (v.x - mean) * rstd * w.x + bb.x;
    v.y = (v.y - mean) * rstd * w.y + bb.y;
    v.z = (v.z - mean) * rstd * w.z + bb.z;
    v.w = (v.w - mean) * rstd * w.w + bb.w;
    ((float4*)out)[i4] = v;
}

extern "C" void kernel_launch(void* const* d_in, const int* in_sizes, int n_in,
                              void* d_out, int out_size, void* d_ws, size_t ws_size,
                              hipStream_t stream) {
    const float* x    = (const float*)d_in[0];
    const float* wqkv = (const float*)d_in[1];
    const float* wout = (const float*)d_in[2];
    const float* bout = (const float*)d_in[3];
    const float* gw   = (const float*)d_in[4];
    const float* gb   = (const float*)d_in[5];
    float* out = (float*)d_out;
    char* wsb  = (char*)d_ws;

    hipMemsetAsync(wsb + CTXF_B, 0, ZERO_BYTES, stream);
    k_prep<<<192, 256, 0, stream>>>(wqkv, wout, wsb);
    k_pass1<<<1024, 256, 0, stream>>>(x, wsb);
    k_ctxnorm<<<128, 256, 0, stream>>>(wsb);
    k_pass2<<<2048, 256, 0, stream>>>(x, bout, wsb, out);
    k_gnfinal<<<1, 64, 0, stream>>>(wsb);
    k_gnorm<<<16384, 256, 0, stream>>>(out, wsb, gw, gb);
}